// Round 11
// baseline (4652.596 us; speedup 1.0000x reference)
//
#include <hip/hip_runtime.h>
#include <stdint.h>

#define BB 2048
#define FF 4096
#define KK 64

#define INV_DEPTH 50   // n <= 49 -> at most 50 inversion draws per k
#define BTRS_DEPTH 16  // precomputed BTRS trials; continuation chain beyond
#define ROWS 64        // rows per block (512 threads)

// ---------------- threefry2x32 (JAX flavor) ----------------
__host__ __device__ __forceinline__ uint32_t rotl32(uint32_t v, int n) {
  return (v << n) | (v >> (32 - n));
}

__host__ __device__ __forceinline__ void tf2x32(uint32_t key0, uint32_t key1,
                                                uint32_t c0, uint32_t c1,
                                                uint32_t& o0, uint32_t& o1) {
  uint32_t ks2 = key0 ^ key1 ^ 0x1BD11BDAu;
  uint32_t x0 = c0 + key0, x1 = c1 + key1;
#define TFR(r) { x0 += x1; x1 = rotl32(x1, (r)); x1 ^= x0; }
  TFR(13) TFR(15) TFR(26) TFR(6)
  x0 += key1; x1 += ks2 + 1u;
  TFR(17) TFR(29) TFR(16) TFR(24)
  x0 += ks2; x1 += key0 + 2u;
  TFR(13) TFR(15) TFR(26) TFR(6)
  x0 += key0; x1 += key1 + 3u;
  TFR(17) TFR(29) TFR(16) TFR(24)
  x0 += key1; x1 += ks2 + 4u;
  TFR(13) TFR(15) TFR(26) TFR(6)
  x0 += ks2; x1 += key0 + 5u;
#undef TFR
  o0 = x0; o1 = x1;
}

__host__ __device__ __forceinline__ void key_child(uint32_t k0, uint32_t k1, uint32_t idx,
                                                   uint32_t& o0, uint32_t& o1) {
  tf2x32(k0, k1, 0u, idx, o0, o1);
}

__device__ __forceinline__ uint32_t rbits(uint32_t k0, uint32_t k1, uint32_t e) {
  uint32_t a, b;
  tf2x32(k0, k1, 0u, e, a, b);
  return a ^ b;
}

__device__ __forceinline__ float u01_from_bits(uint32_t bits) {
  uint32_t fb = (bits >> 9) | 0x3f800000u;
  return __fsub_rn(__uint_as_float(fb), 1.0f);   // [0, 1)
}

// XLA ErfInv (f32, Giles) — exact coefficient replication, no FMA contraction
__device__ __forceinline__ float erfinv_f32(float x) {
  float w = -log1pf(-__fmul_rn(x, x));
  float p;
  if (w < 5.0f) {
    w = __fsub_rn(w, 2.5f);
    p = 2.81022636e-08f;
    p = __fadd_rn(3.43273939e-07f, __fmul_rn(p, w));
    p = __fadd_rn(-3.5233877e-06f, __fmul_rn(p, w));
    p = __fadd_rn(-4.39150654e-06f, __fmul_rn(p, w));
    p = __fadd_rn(0.00021858087f, __fmul_rn(p, w));
    p = __fadd_rn(-0.00125372503f, __fmul_rn(p, w));
    p = __fadd_rn(-0.00417768164f, __fmul_rn(p, w));
    p = __fadd_rn(0.246640727f, __fmul_rn(p, w));
    p = __fadd_rn(1.50140941f, __fmul_rn(p, w));
  } else {
    w = __fsub_rn(sqrtf(w), 3.0f);
    p = -0.000200214257f;
    p = __fadd_rn(0.000100950558f, __fmul_rn(p, w));
    p = __fadd_rn(0.00134934322f, __fmul_rn(p, w));
    p = __fadd_rn(-0.00367342844f, __fmul_rn(p, w));
    p = __fadd_rn(0.00573950773f, __fmul_rn(p, w));
    p = __fadd_rn(-0.0076224613f, __fmul_rn(p, w));
    p = __fadd_rn(0.00943887047f, __fmul_rn(p, w));
    p = __fadd_rn(1.00167406f, __fmul_rn(p, w));
    p = __fadd_rn(2.83297682f, __fmul_rn(p, w));
  }
  return __fmul_rn(p, x);
}

__device__ __forceinline__ float normal_from_key(uint32_t k0, uint32_t k1) {
  float u01 = u01_from_bits(rbits(k0, k1, 0u));
  const float lo = -0.99999994f;             // nextafter(-1,0) in f32
  float u = __fadd_rn(__fmul_rn(u01, 2.0f), lo);
  u = fmaxf(lo, u);
  return __fmul_rn(1.41421356f, erfinv_f32(u));
}

// TFP/JAX stirling_approx_tail
__device__ __forceinline__ float stirling_tail(float k) {
  const float tab[10] = {
    0.0810614667953272f, 0.0413406959554092f, 0.0276779256849983f,
    0.02079067210376509f, 0.0166446911898211f, 0.0138761288230707f,
    0.0118967099458917f, 0.0104112652619720f, 0.00925546218271273f,
    0.00833056343336287f};
  if (k <= 9.0f) return tab[(int)k];
  float kp1 = __fadd_rn(k, 1.0f);
  float kp1sq = __fmul_rn(kp1, kp1);
  float inner = __fsub_rn(0.0027777778f, 0.00079365081f / kp1sq);
  float t = __fsub_rn(0.083333336f, inner / kp1sq);
  return t / kp1;
}

// ---------------- kernels ----------------

__global__ void rowsum_kernel(const float* __restrict__ phi, float* __restrict__ rs) {
  __shared__ float red[256];
  int k = blockIdx.x;
  float s = 0.0f;
  for (int j = threadIdx.x; j < FF; j += 256) s += phi[k * FF + j];
  red[threadIdx.x] = s;
  __syncthreads();
  for (int off = 128; off > 0; off >>= 1) {
    if (threadIdx.x < off) red[threadIdx.x] += red[threadIdx.x + off];
    __syncthreads();
  }
  if (threadIdx.x == 0) rs[k] = red[0];
}

// Precompute wave-uniform key chains for all 64 scan steps.
__global__ void chains_kernel(uint32_t ka0, uint32_t ka1, uint32_t* __restrict__ ch) {
  int k = threadIdx.x;
  if (k >= KK) return;
  uint32_t s0, s1;
  key_child(ka0, ka1, (uint32_t)k, s0, s1);   // scan-step key = split(k_aug, 64)[k]

  uint2* inv = (uint2*)ch + k * INV_DEPTH;
  uint2* b0p = (uint2*)(ch + KK * INV_DEPTH * 2) + k * BTRS_DEPTH;
  uint2* b1p = (uint2*)(ch + KK * INV_DEPTH * 2 + KK * BTRS_DEPTH * 2) + k * BTRS_DEPTH;
  uint2* cont = (uint2*)(ch + KK * INV_DEPTH * 2 + KK * BTRS_DEPTH * 4) + k;

  uint32_t c0 = s0, c1 = s1;
  for (int t = 0; t < INV_DEPTH; ++t) {
    uint32_t a, b, n0, n1;
    key_child(c0, c1, 0u, a, b);     // subkey
    key_child(c0, c1, 1u, n0, n1);   // next key
    inv[t] = make_uint2(a, b);
    c0 = n0; c1 = n1;
  }
  c0 = s0; c1 = s1;
  for (int t = 0; t < BTRS_DEPTH; ++t) {
    uint32_t n0, n1, a0, a1, u0, u1;
    key_child(c0, c1, 0u, n0, n1);
    key_child(c0, c1, 1u, a0, a1);
    key_child(c0, c1, 2u, u0, u1);
    b0p[t] = make_uint2(a0, a1);
    b1p[t] = make_uint2(u0, u1);
    c0 = n0; c1 = n1;
  }
  cont[0] = make_uint2(c0, c1);
}

// Lane-repacked sampler, 512-thread blocks / 64 rows: 3 blocks/CU (24 waves,
// 75% occupancy) with VGPR cap 85 — gives the register allocator headroom
// (1024-thr variant was squeezed to 28 VGPRs -> remat/spill tax suspected).
// u16-packed LDS accumulators (exact integers, order-free). Diagonal claim
// mapping keeps per-wave il distinct. All per-(i,j,k) float math bit-identical.
__global__ __launch_bounds__(512, 6) void sample_kernel(
    const int* __restrict__ xin, const float* __restrict__ theta,
    const float* __restrict__ phi, const float* __restrict__ rs,
    float* __restrict__ m_out, float* __restrict__ x_out,
    const uint32_t* __restrict__ ch) {
  __shared__ float phs[KK][64];            // normalized phi tile (16 KB)
  __shared__ uint32_t xsp[KK][32];         // x_jk packed u16 pairs (8 KB)
  __shared__ float denl[ROWS][64];         // per-element initial denominator (16 KB)
  __shared__ uint32_t mlp[ROWS][32];       // m packed u16 pairs (8 KB)
  __shared__ int ctr;

  const uint2* inv_all = (const uint2*)ch;
  const uint2* b0_all = (const uint2*)(ch + KK * INV_DEPTH * 2);
  const uint2* b1_all = (const uint2*)(ch + KK * INV_DEPTH * 2 + KK * BTRS_DEPTH * 2);
  const uint2* cont_all = (const uint2*)(ch + KK * INV_DEPTH * 2 + KK * BTRS_DEPTH * 4);

  int tid = threadIdx.x;
  int jt = blockIdx.x;              // j tile 0..63
  int rg = blockIdx.y;              // row group 0..31
  int row0 = rg * ROWS;

  for (int idx = tid; idx < KK * 64; idx += 512) {
    int k = idx >> 6, jl = idx & 63;
    phs[k][jl] = phi[k * FF + jt * 64 + jl] / rs[k];
  }
  for (int idx = tid; idx < KK * 32; idx += 512) xsp[idx >> 5][idx & 31] = 0u;
  for (int idx = tid; idx < ROWS * 32; idx += 512) mlp[idx >> 5][idx & 31] = 0u;
  if (tid == 0) ctr = 0;
  __syncthreads();

  // den precompute, lock-step (same fmaf order as before -> bit-exact)
  for (int s = tid; s < ROWS * 64; s += 512) {
    int il = s >> 6, jl = s & 63;
    const float* tr = theta + (size_t)(row0 + il) * KK;
    float d = 0.0f;
    #pragma unroll 8
    for (int kk = 0; kk < KK; ++kk) d = fmaf(tr[kk], phs[kk][jl], d);
    denl[il][jl] = d;
  }
  __syncthreads();

  int mode = 3;          // 0=INV, 1=BTRS, 2=setup, 3=claim, 4=done
  int il = 0, jje = 0, k = 0, ti = 0;
  int jsh = 0;           // 16*(jje&1), precomputed at claim
  uint32_t e = 0;
  bool plth = true;
  float n = 0, den = 0, p = 0, q = 0, l1p = 0, gs = 0, ng = 0;
  float sB = 0, sA = 0, sC = 0, sVr = 0, sR = 0, sAlf = 0, sMm = 0;

  for (int iter = 0; iter < 300000 && __any(mode != 4); ++iter) {
    if (mode == 3) {   // claim next element (diagonal map: distinct il per lane)
      int tt = atomicAdd(&ctr, 1);
      if (tt >= ROWS * 64) {
        mode = 4;
      } else {
        jje = tt & 63;
        il = ((tt >> 6) + jje) & (ROWS - 1);
        jsh = (jje & 1) << 4;
        int gi = row0 + il, gj = jt * 64 + jje;
        n = (float)xin[gi * FF + gj];
        den = denl[il][jje];
        e = (uint32_t)(gi * FF + gj);
        k = 0;
        mode = 2;
      }
    }
    if (mode == 2) {   // channel setup (falls through to first draw)
      float th = theta[(row0 + il) * KK + k];
      p = __fmul_rn(th, phs[k][jje]);
      float ratio = p / fmaxf(den, 1e-30f);
      ratio = fminf(fmaxf(ratio, 0.0f), 1.0f);
      plth = ratio < 0.5f;
      q = plth ? ratio : __fsub_rn(1.0f, ratio);
      if (n <= 0.0f || q <= 0.0f) {
        float chi = plth ? 0.0f : n;
        if (chi != 0.0f) {
          uint32_t c = (uint32_t)(int)chi;
          atomicAdd(&mlp[il][k >> 1], c << ((k & 1) << 4));
          atomicAdd(&xsp[k][jje >> 1], c << jsh);
        }
        mode = 3;
      } else if (__fmul_rn(n, q) <= 10.0f) {
        l1p = log1pf(-q);
        gs = 0.0f; ng = 0.0f; ti = 0;
        mode = 0;
      } else {
        float stddev = sqrtf(__fmul_rn(__fmul_rn(n, q), __fsub_rn(1.0f, q)));
        sB = __fadd_rn(1.15f, __fmul_rn(2.53f, stddev));
        sA = __fadd_rn(__fadd_rn(-0.0873f, __fmul_rn(0.0248f, sB)), __fmul_rn(0.01f, q));
        sC = __fadd_rn(__fmul_rn(n, q), 0.5f);
        sVr = __fsub_rn(0.92f, 4.2f / sB);
        sR = q / __fsub_rn(1.0f, q);
        sAlf = __fmul_rn(__fadd_rn(2.83f, 5.1f / sB), stddev);
        sMm = floorf(__fmul_rn(__fadd_rn(n, 1.0f), q));
        ti = 0;
        mode = 1;
      }
    }
    if (mode == 0) {   // one inversion (geometric) draw
      uint2 sk = inv_all[k * INV_DEPTH + ti];
      ng = __fadd_rn(ng, 1.0f);
      float u = u01_from_bits(rbits(sk.x, sk.y, e));
      float g = ceilf(logf(u) / l1p);
      gs = __fadd_rn(gs, g);
      ti++;
      if (!(gs <= n)) {
        float samp = __fsub_rn(ng, 1.0f);
        float chi = plth ? samp : __fsub_rn(n, samp);
        if (chi != 0.0f) {
          uint32_t c = (uint32_t)(int)chi;
          atomicAdd(&mlp[il][k >> 1], c << ((k & 1) << 4));
          atomicAdd(&xsp[k][jje >> 1], c << jsh);
        }
        n = __fsub_rn(n, chi);
        den = __fsub_rn(den, p);
        k++;
        mode = (n <= 0.0f || k >= KK) ? 3 : 2;
      }
    }
    if (mode == 1) {   // one BTRS trial
      uint32_t s00, s01, s10, s11;
      if (ti < BTRS_DEPTH) {
        uint2 A = b0_all[k * BTRS_DEPTH + ti];
        uint2 Bv = b1_all[k * BTRS_DEPTH + ti];
        s00 = A.x; s01 = A.y; s10 = Bv.x; s11 = Bv.y;
      } else {
        uint2 cc = cont_all[k];
        uint32_t c0 = cc.x, c1 = cc.y;
        for (int tw = BTRS_DEPTH; tw < ti; ++tw) {
          uint32_t a, b; key_child(c0, c1, 0u, a, b); c0 = a; c1 = b;
        }
        key_child(c0, c1, 1u, s00, s01);
        key_child(c0, c1, 2u, s10, s11);
      }
      float u = u01_from_bits(rbits(s00, s01, e));
      float v = u01_from_bits(rbits(s10, s11, e));
      u = __fsub_rn(u, 0.5f);
      float us = __fsub_rn(0.5f, fabsf(u));
      bool accept1 = (us >= 0.07f) && (v <= sVr);
      float kf = floorf(__fadd_rn(__fmul_rn(__fadd_rn(__fmul_rn(2.0f, sA) / us, sB), u), sC));
      bool reject = (kf < 0.0f) || (kf > n);
      float v2 = logf(__fmul_rn(v, sAlf) / __fadd_rn(sA / __fmul_rn(us, us), sB));
      float ub =
        __fadd_rn(
          __fadd_rn(
            __fadd_rn(
              __fmul_rn(__fadd_rn(sMm, 0.5f), logf(__fadd_rn(sMm, 1.0f) / __fmul_rn(sR, __fadd_rn(__fsub_rn(n, sMm), 1.0f)))),
              __fmul_rn(__fadd_rn(n, 1.0f), logf(__fadd_rn(__fsub_rn(n, sMm), 1.0f) / __fadd_rn(__fsub_rn(n, kf), 1.0f)))),
            __fmul_rn(__fadd_rn(kf, 0.5f), logf(__fmul_rn(sR, __fadd_rn(__fsub_rn(n, kf), 1.0f)) / __fadd_rn(kf, 1.0f)))),
          __fsub_rn(__fsub_rn(__fadd_rn(stirling_tail(sMm), stirling_tail(__fsub_rn(n, sMm))),
                              stirling_tail(kf)),
                    stirling_tail(__fsub_rn(n, kf))));
      bool accept2 = v2 <= ub;
      ti++;
      bool done2 = accept1 || ((!reject) && accept2);
      float samp = done2 ? kf : -1.0f;
      if (done2 || ti >= 64) {
        float chi = plth ? samp : __fsub_rn(n, samp);
        if (chi != 0.0f) {
          uint32_t c = (uint32_t)(int)chi;
          atomicAdd(&mlp[il][k >> 1], c << ((k & 1) << 4));
          atomicAdd(&xsp[k][jje >> 1], c << jsh);
        }
        n = __fsub_rn(n, chi);
        den = __fsub_rn(den, p);
        k++;
        mode = (n <= 0.0f || k >= KK) ? 3 : 2;
      }
    }
  }

  __syncthreads();
  // writeback: unpack u16 halves -> float global atomics
  for (int idx = tid; idx < ROWS * 32; idx += 512) {
    int il2 = idx >> 5, kp = idx & 31;
    uint32_t v = mlp[il2][kp];
    float lo = (float)(v & 0xFFFFu), hi = (float)(v >> 16);
    if (lo != 0.0f) atomicAdd(&m_out[(row0 + il2) * KK + kp * 2], lo);
    if (hi != 0.0f) atomicAdd(&m_out[(row0 + il2) * KK + kp * 2 + 1], hi);
  }
  for (int idx = tid; idx < KK * 32; idx += 512) {
    int k2 = idx >> 5, jp = idx & 31;
    uint32_t v = xsp[k2][jp];
    float lo = (float)(v & 0xFFFFu), hi = (float)(v >> 16);
    if (lo != 0.0f) atomicAdd(&x_out[k2 * FF + jt * 64 + jp * 2], lo);
    if (hi != 0.0f) atomicAdd(&x_out[k2 * FF + jt * 64 + jp * 2 + 1], hi);
  }
}

// loggamma (Marsaglia-Tsang, log_space) per element of (K,F); alpha = x + 1 >= 1
__global__ void gamma_kernel(float* __restrict__ xphi, uint32_t kd0, uint32_t kd1) {
  int e = blockIdx.x * blockDim.x + threadIdx.x;
  if (e >= KK * FF) return;
  float alpha = __fadd_rn(xphi[e], 1.0f);

  uint32_t k0, k1;
  key_child(kd0, kd1, (uint32_t)e, k0, k1);   // keys = split(k_dir, K*F)[e]

  uint32_t nk0, nk1;
  key_child(k0, k1, 0u, nk0, nk1);   // key, subkey = split(key); boost unused (alpha>=1)
  k0 = nk0; k1 = nk1;

  float d = __fsub_rn(alpha, 0.33333334f);
  float cc = 0.33333334f / sqrtf(__fmul_rn(9.0f, d));

  float X = 0.0f, V = 1.0f, U = 2.0f;
  for (int t = 0; t < 256; ++t) {
    bool c1 = U >= __fsub_rn(1.0f, __fmul_rn(0.0331f, __fmul_rn(X, X)));
    bool c2 = logf(U) >= __fadd_rn(__fmul_rn(X, 0.5f),
                                   __fmul_rn(d, __fadd_rn(__fsub_rn(1.0f, V), logf(V))));
    if (!(c1 && c2)) break;
    uint32_t b0, b1, xk0, xk1, Uk0, Uk1;
    key_child(k0, k1, 0u, b0, b1);   // key, x_key, U_key = split(key, 3)
    key_child(k0, k1, 1u, xk0, xk1);
    key_child(k0, k1, 2u, Uk0, Uk1);
    k0 = b0; k1 = b1;
    float x = 0.0f, v = -1.0f;
    uint32_t ik0 = xk0, ik1 = xk1;
    for (int s = 0; s < 16 && v <= 0.0f; ++s) {
      uint32_t n2a, n2b, sb0, sb1;
      key_child(ik0, ik1, 0u, n2a, n2b);  // key, subkey = split(key)
      key_child(ik0, ik1, 1u, sb0, sb1);
      ik0 = n2a; ik1 = n2b;
      x = normal_from_key(sb0, sb1);
      v = __fadd_rn(1.0f, __fmul_rn(x, cc));
    }
    X = __fmul_rn(x, x);
    V = __fmul_rn(__fmul_rn(v, v), v);
    U = u01_from_bits(rbits(Uk0, Uk1, 0u));
  }
  xphi[e] = __fadd_rn(logf(d), logf(V));  // log-space sample, boost = 0 for alpha>=1
}

// dirichlet normalize: phi = exp(lg - logsumexp(lg, axis=-1))
__global__ void rownorm_kernel(float* __restrict__ lg) {
  __shared__ float red[256];
  int k = blockIdx.x;
  float* p = lg + (size_t)k * FF;
  float mx = -INFINITY;
  for (int j = threadIdx.x; j < FF; j += 256) mx = fmaxf(mx, p[j]);
  red[threadIdx.x] = mx;
  __syncthreads();
  for (int off = 128; off > 0; off >>= 1) {
    if (threadIdx.x < off) red[threadIdx.x] = fmaxf(red[threadIdx.x], red[threadIdx.x + off]);
    __syncthreads();
  }
  mx = red[0];
  __syncthreads();
  float s = 0.0f;
  for (int j = threadIdx.x; j < FF; j += 256) s += expf(__fsub_rn(p[j], mx));
  red[threadIdx.x] = s;
  __syncthreads();
  for (int off = 128; off > 0; off >>= 1) {
    if (threadIdx.x < off) red[threadIdx.x] += red[threadIdx.x + off];
    __syncthreads();
  }
  float lse = __fadd_rn(logf(red[0]), mx);
  __syncthreads();
  for (int j = threadIdx.x; j < FF; j += 256) p[j] = expf(__fsub_rn(p[j], lse));
}

extern "C" void kernel_launch(void* const* d_in, const int* in_sizes, int n_in,
                              void* d_out, int out_size, void* d_ws, size_t ws_size,
                              hipStream_t stream) {
  (void)in_sizes; (void)n_in; (void)ws_size;
  const int* xin = (const int*)d_in[0];
  const float* theta = (const float*)d_in[1];
  const float* phi = (const float*)d_in[2];
  float* out = (float*)d_out;
  float* m_out = out;                         // (B, K)
  float* xphi = out + (size_t)BB * KK;        // (K, F): x counts -> loggamma -> phi_new
  float* rs = (float*)d_ws;                   // 64 floats
  uint32_t* chains = (uint32_t*)d_ws + 64;    // 42.5 KB of key chains

  // root key: jax.random.key(42) = (0, 42); k_aug, k_dir = split(root)
  uint32_t ka0, ka1, kd0, kd1;
  tf2x32(0u, 42u, 0u, 0u, ka0, ka1);
  tf2x32(0u, 42u, 0u, 1u, kd0, kd1);

  hipMemsetAsync(d_out, 0, (size_t)out_size * sizeof(float), stream);
  hipLaunchKernelGGL(rowsum_kernel, dim3(KK), dim3(256), 0, stream, phi, rs);
  hipLaunchKernelGGL(chains_kernel, dim3(1), dim3(64), 0, stream, ka0, ka1, chains);
  hipLaunchKernelGGL(sample_kernel, dim3(64, BB / ROWS), dim3(512), 0, stream,
                     xin, theta, phi, rs, m_out, xphi, chains);
  hipLaunchKernelGGL(gamma_kernel, dim3((KK * FF) / 256), dim3(256), 0, stream, xphi, kd0, kd1);
  hipLaunchKernelGGL(rownorm_kernel, dim3(KK), dim3(256), 0, stream, xphi);
}

// Round 12
// 4476.126 us; speedup vs baseline: 1.0394x; 1.0394x over previous
//
#include <hip/hip_runtime.h>
#include <stdint.h>

#define BB 2048
#define FF 4096
#define KK 64

#define INV_DEPTH 50   // n <= 49 -> at most 50 inversion draws per k
#define BTRS_DEPTH 16  // precomputed BTRS trials; continuation chain beyond
#define ROWS 128       // rows per block (1024 threads)
#define PARK_CAP 512   // deferred-BTRS park list

// ---------------- threefry2x32 (JAX flavor) ----------------
__host__ __device__ __forceinline__ uint32_t rotl32(uint32_t v, int n) {
  return (v << n) | (v >> (32 - n));
}

__host__ __device__ __forceinline__ void tf2x32(uint32_t key0, uint32_t key1,
                                                uint32_t c0, uint32_t c1,
                                                uint32_t& o0, uint32_t& o1) {
  uint32_t ks2 = key0 ^ key1 ^ 0x1BD11BDAu;
  uint32_t x0 = c0 + key0, x1 = c1 + key1;
#define TFR(r) { x0 += x1; x1 = rotl32(x1, (r)); x1 ^= x0; }
  TFR(13) TFR(15) TFR(26) TFR(6)
  x0 += key1; x1 += ks2 + 1u;
  TFR(17) TFR(29) TFR(16) TFR(24)
  x0 += ks2; x1 += key0 + 2u;
  TFR(13) TFR(15) TFR(26) TFR(6)
  x0 += key0; x1 += key1 + 3u;
  TFR(17) TFR(29) TFR(16) TFR(24)
  x0 += key1; x1 += ks2 + 4u;
  TFR(13) TFR(15) TFR(26) TFR(6)
  x0 += ks2; x1 += key0 + 5u;
#undef TFR
  o0 = x0; o1 = x1;
}

__host__ __device__ __forceinline__ void key_child(uint32_t k0, uint32_t k1, uint32_t idx,
                                                   uint32_t& o0, uint32_t& o1) {
  tf2x32(k0, k1, 0u, idx, o0, o1);
}

__device__ __forceinline__ uint32_t rbits(uint32_t k0, uint32_t k1, uint32_t e) {
  uint32_t a, b;
  tf2x32(k0, k1, 0u, e, a, b);
  return a ^ b;
}

__device__ __forceinline__ float u01_from_bits(uint32_t bits) {
  uint32_t fb = (bits >> 9) | 0x3f800000u;
  return __fsub_rn(__uint_as_float(fb), 1.0f);   // [0, 1)
}

// XLA ErfInv (f32, Giles) — exact coefficient replication, no FMA contraction
__device__ __forceinline__ float erfinv_f32(float x) {
  float w = -log1pf(-__fmul_rn(x, x));
  float p;
  if (w < 5.0f) {
    w = __fsub_rn(w, 2.5f);
    p = 2.81022636e-08f;
    p = __fadd_rn(3.43273939e-07f, __fmul_rn(p, w));
    p = __fadd_rn(-3.5233877e-06f, __fmul_rn(p, w));
    p = __fadd_rn(-4.39150654e-06f, __fmul_rn(p, w));
    p = __fadd_rn(0.00021858087f, __fmul_rn(p, w));
    p = __fadd_rn(-0.00125372503f, __fmul_rn(p, w));
    p = __fadd_rn(-0.00417768164f, __fmul_rn(p, w));
    p = __fadd_rn(0.246640727f, __fmul_rn(p, w));
    p = __fadd_rn(1.50140941f, __fmul_rn(p, w));
  } else {
    w = __fsub_rn(sqrtf(w), 3.0f);
    p = -0.000200214257f;
    p = __fadd_rn(0.000100950558f, __fmul_rn(p, w));
    p = __fadd_rn(0.00134934322f, __fmul_rn(p, w));
    p = __fadd_rn(-0.00367342844f, __fmul_rn(p, w));
    p = __fadd_rn(0.00573950773f, __fmul_rn(p, w));
    p = __fadd_rn(-0.0076224613f, __fmul_rn(p, w));
    p = __fadd_rn(0.00943887047f, __fmul_rn(p, w));
    p = __fadd_rn(1.00167406f, __fmul_rn(p, w));
    p = __fadd_rn(2.83297682f, __fmul_rn(p, w));
  }
  return __fmul_rn(p, x);
}

__device__ __forceinline__ float normal_from_key(uint32_t k0, uint32_t k1) {
  float u01 = u01_from_bits(rbits(k0, k1, 0u));
  const float lo = -0.99999994f;             // nextafter(-1,0) in f32
  float u = __fadd_rn(__fmul_rn(u01, 2.0f), lo);
  u = fmaxf(lo, u);
  return __fmul_rn(1.41421356f, erfinv_f32(u));
}

// TFP/JAX stirling_approx_tail
__device__ __forceinline__ float stirling_tail(float k) {
  const float tab[10] = {
    0.0810614667953272f, 0.0413406959554092f, 0.0276779256849983f,
    0.02079067210376509f, 0.0166446911898211f, 0.0138761288230707f,
    0.0118967099458917f, 0.0104112652619720f, 0.00925546218271273f,
    0.00833056343336287f};
  if (k <= 9.0f) return tab[(int)k];
  float kp1 = __fadd_rn(k, 1.0f);
  float kp1sq = __fmul_rn(kp1, kp1);
  float inner = __fsub_rn(0.0027777778f, 0.00079365081f / kp1sq);
  float t = __fsub_rn(0.083333336f, inner / kp1sq);
  return t / kp1;
}

// ---------------- kernels ----------------

__global__ void rowsum_kernel(const float* __restrict__ phi, float* __restrict__ rs) {
  __shared__ float red[256];
  int k = blockIdx.x;
  float s = 0.0f;
  for (int j = threadIdx.x; j < FF; j += 256) s += phi[k * FF + j];
  red[threadIdx.x] = s;
  __syncthreads();
  for (int off = 128; off > 0; off >>= 1) {
    if (threadIdx.x < off) red[threadIdx.x] += red[threadIdx.x + off];
    __syncthreads();
  }
  if (threadIdx.x == 0) rs[k] = red[0];
}

// Precompute wave-uniform key chains for all 64 scan steps.
__global__ void chains_kernel(uint32_t ka0, uint32_t ka1, uint32_t* __restrict__ ch) {
  int k = threadIdx.x;
  if (k >= KK) return;
  uint32_t s0, s1;
  key_child(ka0, ka1, (uint32_t)k, s0, s1);   // scan-step key = split(k_aug, 64)[k]

  uint2* inv = (uint2*)ch + k * INV_DEPTH;
  uint2* b0p = (uint2*)(ch + KK * INV_DEPTH * 2) + k * BTRS_DEPTH;
  uint2* b1p = (uint2*)(ch + KK * INV_DEPTH * 2 + KK * BTRS_DEPTH * 2) + k * BTRS_DEPTH;
  uint2* cont = (uint2*)(ch + KK * INV_DEPTH * 2 + KK * BTRS_DEPTH * 4) + k;

  uint32_t c0 = s0, c1 = s1;
  for (int t = 0; t < INV_DEPTH; ++t) {
    uint32_t a, b, n0, n1;
    key_child(c0, c1, 0u, a, b);     // subkey
    key_child(c0, c1, 1u, n0, n1);   // next key
    inv[t] = make_uint2(a, b);
    c0 = n0; c1 = n1;
  }
  c0 = s0; c1 = s1;
  for (int t = 0; t < BTRS_DEPTH; ++t) {
    uint32_t n0, n1, a0, a1, u0, u1;
    key_child(c0, c1, 0u, n0, n1);
    key_child(c0, c1, 1u, a0, a1);
    key_child(c0, c1, 2u, u0, u1);
    b0p[t] = make_uint2(a0, a1);
    b1p[t] = make_uint2(u0, u1);
    c0 = n0; c1 = n1;
  }
  cont[0] = make_uint2(c0, c1);
}

// 1024-thread lane-repacked sampler (round-9) + BTRS deferral (round-7):
// phase 1 runs claim/setup/inversion only, parking n*q>10 channels; phase 2
// resolves parked elements with the full machine. u16-packed LDS accumulators
// (exact integers, order-free). All per-(i,j,k) float arithmetic bit-identical.
__global__ __launch_bounds__(1024, 8) void sample_kernel(
    const int* __restrict__ xin, const float* __restrict__ theta,
    const float* __restrict__ phi, const float* __restrict__ rs,
    float* __restrict__ m_out, float* __restrict__ x_out,
    const uint32_t* __restrict__ ch) {
  __shared__ float phs[KK][64];            // normalized phi tile (16 KB)
  __shared__ uint32_t xsp[KK][32];         // x_jk packed u16 pairs (8 KB)
  __shared__ float denl[ROWS][64];         // per-element initial denominator (32 KB)
  __shared__ uint32_t mlp[ROWS][32];       // m packed u16 pairs (16 KB)
  __shared__ uint2 park[PARK_CAP];         // deferred-BTRS elements (4 KB)
  __shared__ int ctr, pk_n, pk_claim;

  const uint2* inv_all = (const uint2*)ch;
  const uint2* b0_all = (const uint2*)(ch + KK * INV_DEPTH * 2);
  const uint2* b1_all = (const uint2*)(ch + KK * INV_DEPTH * 2 + KK * BTRS_DEPTH * 2);
  const uint2* cont_all = (const uint2*)(ch + KK * INV_DEPTH * 2 + KK * BTRS_DEPTH * 4);

  int tid = threadIdx.x;
  int jt = blockIdx.x;              // j tile 0..63
  int rg = blockIdx.y;              // row group 0..15
  int row0 = rg * ROWS;

  for (int idx = tid; idx < KK * 64; idx += 1024) {
    int k = idx >> 6, jl = idx & 63;
    phs[k][jl] = phi[k * FF + jt * 64 + jl] / rs[k];
  }
  for (int idx = tid; idx < KK * 32; idx += 1024) xsp[idx >> 5][idx & 31] = 0u;
  for (int idx = tid; idx < ROWS * 32; idx += 1024) mlp[idx >> 5][idx & 31] = 0u;
  if (tid == 0) { ctr = 0; pk_n = 0; pk_claim = 0; }
  __syncthreads();

  // den precompute, lock-step (same fmaf order as before -> bit-exact)
  for (int s = tid; s < ROWS * 64; s += 1024) {
    int il = s >> 6, jl = s & 63;
    const float* tr = theta + (size_t)(row0 + il) * KK;
    float d = 0.0f;
    #pragma unroll 8
    for (int kk = 0; kk < KK; ++kk) d = fmaf(tr[kk], phs[kk][jl], d);
    denl[il][jl] = d;
  }
  __syncthreads();

  int mode = 3;          // 0=INV, 1=BTRS, 2=setup, 3=claim, 4=done
  int il = 0, jje = 0, k = 0, ti = 0;
  int jsh = 0;
  uint32_t e = 0;
  bool plth = true;
  float n = 0, den = 0, p = 0, q = 0, l1p = 0, gs = 0, ng = 0;
  float sB = 0, sA = 0, sC = 0, sVr = 0, sR = 0, sAlf = 0, sMm = 0;

  // ---------- phase 1: claim/setup/inversion; BTRS parked ----------
  for (int iter = 0; iter < 300000 && __any(mode != 4); ++iter) {
    if (mode == 3) {   // claim next element (diagonal map: distinct il per lane)
      int tt = atomicAdd(&ctr, 1);
      if (tt >= ROWS * 64) {
        mode = 4;
      } else {
        jje = tt & 63;
        il = ((tt >> 6) + jje) & (ROWS - 1);
        jsh = (jje & 1) << 4;
        int gi = row0 + il, gj = jt * 64 + jje;
        n = (float)xin[gi * FF + gj];
        den = denl[il][jje];
        e = (uint32_t)(gi * FF + gj);
        k = 0;
        mode = 2;
      }
    }
    if (mode == 2) {   // channel setup (falls through to first draw)
      float th = theta[(row0 + il) * KK + k];
      p = __fmul_rn(th, phs[k][jje]);
      float ratio = p / fmaxf(den, 1e-30f);
      ratio = fminf(fmaxf(ratio, 0.0f), 1.0f);
      plth = ratio < 0.5f;
      q = plth ? ratio : __fsub_rn(1.0f, ratio);
      if (n <= 0.0f || q <= 0.0f) {
        float chi = plth ? 0.0f : n;
        if (chi != 0.0f) {
          uint32_t c = (uint32_t)(int)chi;
          atomicAdd(&mlp[il][k >> 1], c << ((k & 1) << 4));
          atomicAdd(&xsp[k][jje >> 1], c << jsh);
        }
        mode = 3;
      } else if (__fmul_rn(n, q) <= 10.0f) {
        l1p = log1pf(-q);
        gs = 0.0f; ng = 0.0f; ti = 0;
        mode = 0;
      } else {
        int slot = atomicAdd(&pk_n, 1);
        if (slot < PARK_CAP) {   // park: il(7b)|jje(6b)|k(6b)|n(6b), den raw f32
          park[slot] = make_uint2((uint32_t)il | ((uint32_t)jje << 7) |
                                  ((uint32_t)k << 13) | ((uint32_t)(int)n << 19),
                                  __float_as_uint(den));
          mode = 3;
        } else {                 // overflow fallback: inline BTRS
          float stddev = sqrtf(__fmul_rn(__fmul_rn(n, q), __fsub_rn(1.0f, q)));
          sB = __fadd_rn(1.15f, __fmul_rn(2.53f, stddev));
          sA = __fadd_rn(__fadd_rn(-0.0873f, __fmul_rn(0.0248f, sB)), __fmul_rn(0.01f, q));
          sC = __fadd_rn(__fmul_rn(n, q), 0.5f);
          sVr = __fsub_rn(0.92f, 4.2f / sB);
          sR = q / __fsub_rn(1.0f, q);
          sAlf = __fmul_rn(__fadd_rn(2.83f, 5.1f / sB), stddev);
          sMm = floorf(__fmul_rn(__fadd_rn(n, 1.0f), q));
          ti = 0;
          mode = 1;
        }
      }
    }
    if (mode == 0) {   // one inversion (geometric) draw
      uint2 sk = inv_all[k * INV_DEPTH + ti];
      ng = __fadd_rn(ng, 1.0f);
      float u = u01_from_bits(rbits(sk.x, sk.y, e));
      float g = ceilf(logf(u) / l1p);
      gs = __fadd_rn(gs, g);
      ti++;
      if (!(gs <= n)) {
        float samp = __fsub_rn(ng, 1.0f);
        float chi = plth ? samp : __fsub_rn(n, samp);
        if (chi != 0.0f) {
          uint32_t c = (uint32_t)(int)chi;
          atomicAdd(&mlp[il][k >> 1], c << ((k & 1) << 4));
          atomicAdd(&xsp[k][jje >> 1], c << jsh);
        }
        n = __fsub_rn(n, chi);
        den = __fsub_rn(den, p);
        k++;
        mode = (n <= 0.0f || k >= KK) ? 3 : 2;
      }
    }
    if (mode == 1) {   // BTRS trial (rare: overflow only)
      uint32_t s00, s01, s10, s11;
      if (ti < BTRS_DEPTH) {
        uint2 A = b0_all[k * BTRS_DEPTH + ti];
        uint2 Bv = b1_all[k * BTRS_DEPTH + ti];
        s00 = A.x; s01 = A.y; s10 = Bv.x; s11 = Bv.y;
      } else {
        uint2 cc = cont_all[k];
        uint32_t c0 = cc.x, c1 = cc.y;
        for (int tw = BTRS_DEPTH; tw < ti; ++tw) {
          uint32_t a, b; key_child(c0, c1, 0u, a, b); c0 = a; c1 = b;
        }
        key_child(c0, c1, 1u, s00, s01);
        key_child(c0, c1, 2u, s10, s11);
      }
      float u = u01_from_bits(rbits(s00, s01, e));
      float v = u01_from_bits(rbits(s10, s11, e));
      u = __fsub_rn(u, 0.5f);
      float us = __fsub_rn(0.5f, fabsf(u));
      bool accept1 = (us >= 0.07f) && (v <= sVr);
      float kf = floorf(__fadd_rn(__fmul_rn(__fadd_rn(__fmul_rn(2.0f, sA) / us, sB), u), sC));
      bool reject = (kf < 0.0f) || (kf > n);
      float v2 = logf(__fmul_rn(v, sAlf) / __fadd_rn(sA / __fmul_rn(us, us), sB));
      float ub =
        __fadd_rn(
          __fadd_rn(
            __fadd_rn(
              __fmul_rn(__fadd_rn(sMm, 0.5f), logf(__fadd_rn(sMm, 1.0f) / __fmul_rn(sR, __fadd_rn(__fsub_rn(n, sMm), 1.0f)))),
              __fmul_rn(__fadd_rn(n, 1.0f), logf(__fadd_rn(__fsub_rn(n, sMm), 1.0f) / __fadd_rn(__fsub_rn(n, kf), 1.0f)))),
            __fmul_rn(__fadd_rn(kf, 0.5f), logf(__fmul_rn(sR, __fadd_rn(__fsub_rn(n, kf), 1.0f)) / __fadd_rn(kf, 1.0f)))),
          __fsub_rn(__fsub_rn(__fadd_rn(stirling_tail(sMm), stirling_tail(__fsub_rn(n, sMm))),
                              stirling_tail(kf)),
                    stirling_tail(__fsub_rn(n, kf))));
      bool accept2 = v2 <= ub;
      ti++;
      bool done2 = accept1 || ((!reject) && accept2);
      float samp = done2 ? kf : -1.0f;
      if (done2 || ti >= 64) {
        float chi = plth ? samp : __fsub_rn(n, samp);
        if (chi != 0.0f) {
          uint32_t c = (uint32_t)(int)chi;
          atomicAdd(&mlp[il][k >> 1], c << ((k & 1) << 4));
          atomicAdd(&xsp[k][jje >> 1], c << jsh);
        }
        n = __fsub_rn(n, chi);
        den = __fsub_rn(den, p);
        k++;
        mode = (n <= 0.0f || k >= KK) ? 3 : 2;
      }
    }
  }

  __syncthreads();   // park list fully visible

  // ---------- phase 2: resolve parked elements (full machine) ----------
  int pk_total = min(pk_n, PARK_CAP);
  mode = 3;
  for (int iter = 0; iter < 300000 && __any(mode != 4); ++iter) {
    if (mode == 3) {   // claim parked element
      int tt = atomicAdd(&pk_claim, 1);
      if (tt >= pk_total) {
        mode = 4;
      } else {
        uint2 st = park[tt];
        il = (int)(st.x & 127u);
        jje = (int)((st.x >> 7) & 63u);
        k = (int)((st.x >> 13) & 63u);
        n = (float)(int)((st.x >> 19) & 63u);
        den = __uint_as_float(st.y);
        jsh = (jje & 1) << 4;
        e = (uint32_t)((row0 + il) * FF + (jt * 64 + jje));
        mode = 2;
      }
    }
    if (mode == 2) {   // channel setup (recompute; bit-exact same inputs)
      float th = theta[(row0 + il) * KK + k];
      p = __fmul_rn(th, phs[k][jje]);
      float ratio = p / fmaxf(den, 1e-30f);
      ratio = fminf(fmaxf(ratio, 0.0f), 1.0f);
      plth = ratio < 0.5f;
      q = plth ? ratio : __fsub_rn(1.0f, ratio);
      if (n <= 0.0f || q <= 0.0f) {
        float chi = plth ? 0.0f : n;
        if (chi != 0.0f) {
          uint32_t c = (uint32_t)(int)chi;
          atomicAdd(&mlp[il][k >> 1], c << ((k & 1) << 4));
          atomicAdd(&xsp[k][jje >> 1], c << jsh);
        }
        mode = 3;
      } else if (__fmul_rn(n, q) <= 10.0f) {
        l1p = log1pf(-q);
        gs = 0.0f; ng = 0.0f; ti = 0;
        mode = 0;
      } else {
        float stddev = sqrtf(__fmul_rn(__fmul_rn(n, q), __fsub_rn(1.0f, q)));
        sB = __fadd_rn(1.15f, __fmul_rn(2.53f, stddev));
        sA = __fadd_rn(__fadd_rn(-0.0873f, __fmul_rn(0.0248f, sB)), __fmul_rn(0.01f, q));
        sC = __fadd_rn(__fmul_rn(n, q), 0.5f);
        sVr = __fsub_rn(0.92f, 4.2f / sB);
        sR = q / __fsub_rn(1.0f, q);
        sAlf = __fmul_rn(__fadd_rn(2.83f, 5.1f / sB), stddev);
        sMm = floorf(__fmul_rn(__fadd_rn(n, 1.0f), q));
        ti = 0;
        mode = 1;
      }
    }
    if (mode == 0) {   // inversion draw
      uint2 sk = inv_all[k * INV_DEPTH + ti];
      ng = __fadd_rn(ng, 1.0f);
      float u = u01_from_bits(rbits(sk.x, sk.y, e));
      float g = ceilf(logf(u) / l1p);
      gs = __fadd_rn(gs, g);
      ti++;
      if (!(gs <= n)) {
        float samp = __fsub_rn(ng, 1.0f);
        float chi = plth ? samp : __fsub_rn(n, samp);
        if (chi != 0.0f) {
          uint32_t c = (uint32_t)(int)chi;
          atomicAdd(&mlp[il][k >> 1], c << ((k & 1) << 4));
          atomicAdd(&xsp[k][jje >> 1], c << jsh);
        }
        n = __fsub_rn(n, chi);
        den = __fsub_rn(den, p);
        k++;
        mode = (n <= 0.0f || k >= KK) ? 3 : 2;
      }
    }
    if (mode == 1) {   // BTRS trial
      uint32_t s00, s01, s10, s11;
      if (ti < BTRS_DEPTH) {
        uint2 A = b0_all[k * BTRS_DEPTH + ti];
        uint2 Bv = b1_all[k * BTRS_DEPTH + ti];
        s00 = A.x; s01 = A.y; s10 = Bv.x; s11 = Bv.y;
      } else {
        uint2 cc = cont_all[k];
        uint32_t c0 = cc.x, c1 = cc.y;
        for (int tw = BTRS_DEPTH; tw < ti; ++tw) {
          uint32_t a, b; key_child(c0, c1, 0u, a, b); c0 = a; c1 = b;
        }
        key_child(c0, c1, 1u, s00, s01);
        key_child(c0, c1, 2u, s10, s11);
      }
      float u = u01_from_bits(rbits(s00, s01, e));
      float v = u01_from_bits(rbits(s10, s11, e));
      u = __fsub_rn(u, 0.5f);
      float us = __fsub_rn(0.5f, fabsf(u));
      bool accept1 = (us >= 0.07f) && (v <= sVr);
      float kf = floorf(__fadd_rn(__fmul_rn(__fadd_rn(__fmul_rn(2.0f, sA) / us, sB), u), sC));
      bool reject = (kf < 0.0f) || (kf > n);
      float v2 = logf(__fmul_rn(v, sAlf) / __fadd_rn(sA / __fmul_rn(us, us), sB));
      float ub =
        __fadd_rn(
          __fadd_rn(
            __fadd_rn(
              __fmul_rn(__fadd_rn(sMm, 0.5f), logf(__fadd_rn(sMm, 1.0f) / __fmul_rn(sR, __fadd_rn(__fsub_rn(n, sMm), 1.0f)))),
              __fmul_rn(__fadd_rn(n, 1.0f), logf(__fadd_rn(__fsub_rn(n, sMm), 1.0f) / __fadd_rn(__fsub_rn(n, kf), 1.0f)))),
            __fmul_rn(__fadd_rn(kf, 0.5f), logf(__fmul_rn(sR, __fadd_rn(__fsub_rn(n, kf), 1.0f)) / __fadd_rn(kf, 1.0f)))),
          __fsub_rn(__fsub_rn(__fadd_rn(stirling_tail(sMm), stirling_tail(__fsub_rn(n, sMm))),
                              stirling_tail(kf)),
                    stirling_tail(__fsub_rn(n, kf))));
      bool accept2 = v2 <= ub;
      ti++;
      bool done2 = accept1 || ((!reject) && accept2);
      float samp = done2 ? kf : -1.0f;
      if (done2 || ti >= 64) {
        float chi = plth ? samp : __fsub_rn(n, samp);
        if (chi != 0.0f) {
          uint32_t c = (uint32_t)(int)chi;
          atomicAdd(&mlp[il][k >> 1], c << ((k & 1) << 4));
          atomicAdd(&xsp[k][jje >> 1], c << jsh);
        }
        n = __fsub_rn(n, chi);
        den = __fsub_rn(den, p);
        k++;
        mode = (n <= 0.0f || k >= KK) ? 3 : 2;
      }
    }
  }

  __syncthreads();
  // writeback: unpack u16 halves -> float global atomics
  for (int idx = tid; idx < ROWS * 32; idx += 1024) {
    int il2 = idx >> 5, kp = idx & 31;
    uint32_t v = mlp[il2][kp];
    float lo = (float)(v & 0xFFFFu), hi = (float)(v >> 16);
    if (lo != 0.0f) atomicAdd(&m_out[(row0 + il2) * KK + kp * 2], lo);
    if (hi != 0.0f) atomicAdd(&m_out[(row0 + il2) * KK + kp * 2 + 1], hi);
  }
  for (int idx = tid; idx < KK * 32; idx += 1024) {
    int k2 = idx >> 5, jp = idx & 31;
    uint32_t v = xsp[k2][jp];
    float lo = (float)(v & 0xFFFFu), hi = (float)(v >> 16);
    if (lo != 0.0f) atomicAdd(&x_out[k2 * FF + jt * 64 + jp * 2], lo);
    if (hi != 0.0f) atomicAdd(&x_out[k2 * FF + jt * 64 + jp * 2 + 1], hi);
  }
}

// loggamma (Marsaglia-Tsang, log_space) per element of (K,F); alpha = x + 1 >= 1
__global__ void gamma_kernel(float* __restrict__ xphi, uint32_t kd0, uint32_t kd1) {
  int e = blockIdx.x * blockDim.x + threadIdx.x;
  if (e >= KK * FF) return;
  float alpha = __fadd_rn(xphi[e], 1.0f);

  uint32_t k0, k1;
  key_child(kd0, kd1, (uint32_t)e, k0, k1);   // keys = split(k_dir, K*F)[e]

  uint32_t nk0, nk1;
  key_child(k0, k1, 0u, nk0, nk1);   // key, subkey = split(key); boost unused (alpha>=1)
  k0 = nk0; k1 = nk1;

  float d = __fsub_rn(alpha, 0.33333334f);
  float cc = 0.33333334f / sqrtf(__fmul_rn(9.0f, d));

  float X = 0.0f, V = 1.0f, U = 2.0f;
  for (int t = 0; t < 256; ++t) {
    bool c1 = U >= __fsub_rn(1.0f, __fmul_rn(0.0331f, __fmul_rn(X, X)));
    bool c2 = logf(U) >= __fadd_rn(__fmul_rn(X, 0.5f),
                                   __fmul_rn(d, __fadd_rn(__fsub_rn(1.0f, V), logf(V))));
    if (!(c1 && c2)) break;
    uint32_t b0, b1, xk0, xk1, Uk0, Uk1;
    key_child(k0, k1, 0u, b0, b1);   // key, x_key, U_key = split(key, 3)
    key_child(k0, k1, 1u, xk0, xk1);
    key_child(k0, k1, 2u, Uk0, Uk1);
    k0 = b0; k1 = b1;
    float x = 0.0f, v = -1.0f;
    uint32_t ik0 = xk0, ik1 = xk1;
    for (int s = 0; s < 16 && v <= 0.0f; ++s) {
      uint32_t n2a, n2b, sb0, sb1;
      key_child(ik0, ik1, 0u, n2a, n2b);  // key, subkey = split(key)
      key_child(ik0, ik1, 1u, sb0, sb1);
      ik0 = n2a; ik1 = n2b;
      x = normal_from_key(sb0, sb1);
      v = __fadd_rn(1.0f, __fmul_rn(x, cc));
    }
    X = __fmul_rn(x, x);
    V = __fmul_rn(__fmul_rn(v, v), v);
    U = u01_from_bits(rbits(Uk0, Uk1, 0u));
  }
  xphi[e] = __fadd_rn(logf(d), logf(V));  // log-space sample, boost = 0 for alpha>=1
}

// dirichlet normalize: phi = exp(lg - logsumexp(lg, axis=-1))
__global__ void rownorm_kernel(float* __restrict__ lg) {
  __shared__ float red[256];
  int k = blockIdx.x;
  float* p = lg + (size_t)k * FF;
  float mx = -INFINITY;
  for (int j = threadIdx.x; j < FF; j += 256) mx = fmaxf(mx, p[j]);
  red[threadIdx.x] = mx;
  __syncthreads();
  for (int off = 128; off > 0; off >>= 1) {
    if (threadIdx.x < off) red[threadIdx.x] = fmaxf(red[threadIdx.x], red[threadIdx.x + off]);
    __syncthreads();
  }
  mx = red[0];
  __syncthreads();
  float s = 0.0f;
  for (int j = threadIdx.x; j < FF; j += 256) s += expf(__fsub_rn(p[j], mx));
  red[threadIdx.x] = s;
  __syncthreads();
  for (int off = 128; off > 0; off >>= 1) {
    if (threadIdx.x < off) red[threadIdx.x] += red[threadIdx.x + off];
    __syncthreads();
  }
  float lse = __fadd_rn(logf(red[0]), mx);
  __syncthreads();
  for (int j = threadIdx.x; j < FF; j += 256) p[j] = expf(__fsub_rn(p[j], lse));
}

extern "C" void kernel_launch(void* const* d_in, const int* in_sizes, int n_in,
                              void* d_out, int out_size, void* d_ws, size_t ws_size,
                              hipStream_t stream) {
  (void)in_sizes; (void)n_in; (void)ws_size;
  const int* xin = (const int*)d_in[0];
  const float* theta = (const float*)d_in[1];
  const float* phi = (const float*)d_in[2];
  float* out = (float*)d_out;
  float* m_out = out;                         // (B, K)
  float* xphi = out + (size_t)BB * KK;        // (K, F): x counts -> loggamma -> phi_new
  float* rs = (float*)d_ws;                   // 64 floats
  uint32_t* chains = (uint32_t*)d_ws + 64;    // 42.5 KB of key chains

  // root key: jax.random.key(42) = (0, 42); k_aug, k_dir = split(root)
  uint32_t ka0, ka1, kd0, kd1;
  tf2x32(0u, 42u, 0u, 0u, ka0, ka1);
  tf2x32(0u, 42u, 0u, 1u, kd0, kd1);

  hipMemsetAsync(d_out, 0, (size_t)out_size * sizeof(float), stream);
  hipLaunchKernelGGL(rowsum_kernel, dim3(KK), dim3(256), 0, stream, phi, rs);
  hipLaunchKernelGGL(chains_kernel, dim3(1), dim3(64), 0, stream, ka0, ka1, chains);
  hipLaunchKernelGGL(sample_kernel, dim3(64, BB / ROWS), dim3(1024), 0, stream,
                     xin, theta, phi, rs, m_out, xphi, chains);
  hipLaunchKernelGGL(gamma_kernel, dim3((KK * FF) / 256), dim3(256), 0, stream, xphi, kd0, kd1);
  hipLaunchKernelGGL(rownorm_kernel, dim3(KK), dim3(256), 0, stream, xphi);
}